// Round 2
// baseline (483.362 us; speedup 1.0000x reference)
//
#include <hip/hip_runtime.h>
#include <hip/hip_bf16.h>

// Transformer-XL block: BS=2, QS=KS=2048, H=1024, NH=16, HD=64
// Derivation: after _left_shift + strict causal mask, for k<=q:
//   score[b,q,k,n] = ((q+rw)·K[k] + (q+rr)·r[S-1-(q-k)]) / 8,  -inf for k>q
// Pipeline: cast -> Wt transpose -> QKV/R GEMMs (fp16 MFMA) -> flash attn
//           with windowed rel-pos matmul -> out GEMM (+residual) -> LayerNorm.

typedef _Float16 f16;
typedef __attribute__((ext_vector_type(8))) _Float16 f16x8;
typedef __attribute__((ext_vector_type(4))) float f32x4;

#define DEV __device__ __forceinline__

// ---------------- cast f32 -> f16 ----------------
__global__ __launch_bounds__(256) void cast_kernel(const float* __restrict__ in,
                                                   f16* __restrict__ out, int n4) {
  int i = blockIdx.x * 256 + threadIdx.x;
  if (i >= n4) return;
  f32x4 v = *(const f32x4*)&in[i * 4];
  f16 o0 = (f16)v[0], o1 = (f16)v[1], o2 = (f16)v[2], o3 = (f16)v[3];
  f16* p = &out[i * 4];
  p[0] = o0; p[1] = o1; p[2] = o2; p[3] = o3;
}

// ---------------- W[k][n] f32 -> WT[n][k] f16 ----------------
__global__ __launch_bounds__(256) void wtrans_kernel(const float* __restrict__ W,
                                                     f16* __restrict__ WT) {
  __shared__ float tile[32][33];
  int k0 = blockIdx.x * 32, n0 = blockIdx.y * 32;
  int tx = threadIdx.x, ty = threadIdx.y;
#pragma unroll
  for (int i = 0; i < 4; ++i)
    tile[ty + i * 8][tx] = W[(size_t)(k0 + ty + i * 8) * 1024 + n0 + tx];
  __syncthreads();
#pragma unroll
  for (int i = 0; i < 4; ++i)
    WT[(size_t)(n0 + ty + i * 8) * 1024 + k0 + tx] = (f16)tile[tx][ty + i * 8];
}

// ---------------- GEMM: out[M,1024] = A[M,1024] @ W, B given as WT[n][k] ----------------
// MODE 0: Q -> out0 = f16(acc+rw[c]), out1 = f16(acc+rr[c])   (natural [m][c])
// MODE 1: K -> out0 natural f16
// MODE 2: V -> out0 = VT[b,n,d,s] (transposed via LDS epilogue)
// MODE 3: R -> out0 natural f16
// MODE 4: O -> fout = acc + xres  (f32, pre-LN)
template <int MODE>
__global__ __launch_bounds__(256) void gemm_kernel(
    const f16* __restrict__ A, const f16* __restrict__ Bw,
    f16* __restrict__ out0, f16* __restrict__ out1,
    float* __restrict__ fout, const float* __restrict__ xres,
    const float* __restrict__ bias0, const float* __restrict__ bias1) {
  constexpr int LD = 72;  // padded row (shorts) to dodge bank conflicts
  __shared__ f16 sm[2 * 128 * LD];
  f16* As = sm;
  f16* Bs = sm + 128 * LD;
  const int tid = threadIdx.x, lane = tid & 63, wv = tid >> 6;
  const int wm = wv >> 1, wn = wv & 1, lg = lane >> 4, ln = lane & 15;
  const int m0 = blockIdx.y * 128, n0 = blockIdx.x * 128;
  f32x4 acc[4][4] = {};
  const int srow = tid >> 1, scb = (tid & 1) * 32;
  const f16* ga = A + (size_t)(m0 + srow) * 1024 + scb;
  const f16* gb = Bw + (size_t)(n0 + srow) * 1024 + scb;
  f16* as_w = &As[srow * LD + scb];
  f16* bs_w = &Bs[srow * LD + scb];

  for (int kt = 0; kt < 16; ++kt) {
    __syncthreads();
#pragma unroll
    for (int i = 0; i < 4; ++i) {
      *(f16x8*)&as_w[i * 8] = *(const f16x8*)&ga[kt * 64 + i * 8];
      *(f16x8*)&bs_w[i * 8] = *(const f16x8*)&gb[kt * 64 + i * 8];
    }
    __syncthreads();
#pragma unroll
    for (int ks = 0; ks < 2; ++ks) {
      f16x8 af[4], bfr[4];
#pragma unroll
      for (int mi = 0; mi < 4; ++mi)
        af[mi] = *(const f16x8*)&As[(wm * 64 + mi * 16 + ln) * LD + ks * 32 + 8 * lg];
#pragma unroll
      for (int ni = 0; ni < 4; ++ni)
        bfr[ni] = *(const f16x8*)&Bs[(wn * 64 + ni * 16 + ln) * LD + ks * 32 + 8 * lg];
#pragma unroll
      for (int mi = 0; mi < 4; ++mi)
#pragma unroll
        for (int ni = 0; ni < 4; ++ni)
          acc[mi][ni] = __builtin_amdgcn_mfma_f32_16x16x32_f16(af[mi], bfr[ni],
                                                               acc[mi][ni], 0, 0, 0);
    }
  }

  if (MODE == 2) {
    // epilogue transpose: T[col_local][m_local] then coalesced rows of VT[b,n,d,s]
    __syncthreads();
    f16* T = sm;  // [128][136]
#pragma unroll
    for (int mi = 0; mi < 4; ++mi)
#pragma unroll
      for (int ni = 0; ni < 4; ++ni)
#pragma unroll
        for (int r = 0; r < 4; ++r) {
          int ml = wm * 64 + mi * 16 + 4 * lg + r;
          int cl = wn * 64 + ni * 16 + ln;
          T[cl * 136 + ml] = (f16)acc[mi][ni][r];
        }
    __syncthreads();
    int cl = tid >> 1, mb = (tid & 1) * 64;
    int gc = n0 + cl, gm = m0 + mb;
    int hh = gc >> 6, dd = gc & 63, bb = gm >> 11, ss = gm & 2047;
    f16* dst = out0 + ((size_t)(bb * 16 + hh) * 64 + dd) * 2048 + ss;
    const f16* srcT = &T[cl * 136 + mb];
#pragma unroll
    for (int i = 0; i < 8; ++i) *(f16x8*)&dst[i * 8] = *(const f16x8*)&srcT[i * 8];
  } else {
#pragma unroll
    for (int mi = 0; mi < 4; ++mi)
#pragma unroll
      for (int ni = 0; ni < 4; ++ni)
#pragma unroll
        for (int r = 0; r < 4; ++r) {
          int m = m0 + wm * 64 + mi * 16 + 4 * lg + r;
          int c = n0 + wn * 64 + ni * 16 + ln;
          float v = acc[mi][ni][r];
          size_t off = (size_t)m * 1024 + c;
          if (MODE == 0) {
            out0[off] = (f16)(v + bias0[c]);
            out1[off] = (f16)(v + bias1[c]);
          } else if (MODE == 1 || MODE == 3) {
            out0[off] = (f16)v;
          } else {  // MODE 4
            fout[off] = v + xres[off];
          }
        }
  }
}

// ---------------- flash attention with rel-pos window ----------------
__global__ __launch_bounds__(256) void attn_kernel(
    const f16* __restrict__ Qw, const f16* __restrict__ Qr,
    const f16* __restrict__ Kb, const f16* __restrict__ VT,
    const f16* __restrict__ Rb, f16* __restrict__ attb) {
  constexpr int KP = 72;
  __shared__ f16 Kl[64 * KP];    // [key][d]
  __shared__ f16 Vl[64 * KP];    // [d][key]
  __shared__ f16 Rl[128 * KP];   // [t][d]  window of r rows jb..jb+127
  __shared__ f16 Ml[64 * 136];   // M[q_local][t]
  __shared__ f16 Pl[64 * KP];    // P[q_local][key]

  const int qt = blockIdx.x, h = blockIdx.y, b = blockIdx.z;
  const int q0 = qt * 64;
  const int tid = threadIdx.x, lane = tid & 63, wv = tid >> 6;
  const int lg = lane >> 4, ln = lane & 15;

  // Q fragments (natural layout, direct from global). Wave wv owns q rows [wv*16, wv*16+16).
  const size_t qoff = ((size_t)(b * 2048 + q0 + wv * 16 + ln) * 16 + h) * 64 + 8 * lg;
  f16x8 aqw[2], aqr[2];
  aqw[0] = *(const f16x8*)&Qw[qoff];
  aqw[1] = *(const f16x8*)&Qw[qoff + 32];
  aqr[0] = *(const f16x8*)&Qr[qoff];
  aqr[1] = *(const f16x8*)&Qr[qoff + 32];

  f32x4 oacc[4] = {};
  float mrun[4] = {-1e30f, -1e30f, -1e30f, -1e30f};
  float lrun[4] = {0.f, 0.f, 0.f, 0.f};

  const int r4 = tid >> 2, c16 = (tid & 3) * 16;  // K/V staging
  const int r2 = tid >> 1, c32 = (tid & 1) * 32;  // R staging

  for (int kt = 0; kt <= qt; ++kt) {
    const int k0 = kt * 64;
    __syncthreads();
    {
      const f16* ksrc = Kb + ((size_t)(b * 2048 + k0 + r4) * 16 + h) * 64 + c16;
      *(f16x8*)&Kl[r4 * KP + c16] = *(const f16x8*)&ksrc[0];
      *(f16x8*)&Kl[r4 * KP + c16 + 8] = *(const f16x8*)&ksrc[8];
      const f16* vsrc = VT + ((size_t)(b * 16 + h) * 64 + r4) * 2048 + k0 + c16;
      *(f16x8*)&Vl[r4 * KP + c16] = *(const f16x8*)&vsrc[0];
      *(f16x8*)&Vl[r4 * KP + c16 + 8] = *(const f16x8*)&vsrc[8];
      const int jb = 2048 - 64 - q0 + k0;
      const int j = jb + r2;
      if (j < 2048) {
        const f16* rsrc = Rb + ((size_t)j * 16 + h) * 64 + c32;
#pragma unroll
        for (int i = 0; i < 4; ++i)
          *(f16x8*)&Rl[r2 * KP + c32 + i * 8] = *(const f16x8*)&rsrc[i * 8];
      } else {
        f16x8 z = {};
#pragma unroll
        for (int i = 0; i < 4; ++i) *(f16x8*)&Rl[r2 * KP + c32 + i * 8] = z;
      }
    }
    __syncthreads();

    // AC = (Q+rw) @ K^T  -> sc[ni] covers keys ni*16+ln, rows 4*lg+r
    f32x4 sc[4] = {};
#pragma unroll
    for (int ks = 0; ks < 2; ++ks)
#pragma unroll
      for (int ni = 0; ni < 4; ++ni) {
        f16x8 kf = *(const f16x8*)&Kl[(ni * 16 + ln) * KP + ks * 32 + 8 * lg];
        sc[ni] = __builtin_amdgcn_mfma_f32_16x16x32_f16(aqw[ks], kf, sc[ni], 0, 0, 0);
      }
    // M window = (Q+rr) @ Rwin^T  (128 wide)
    f32x4 mw[8] = {};
#pragma unroll
    for (int ks = 0; ks < 2; ++ks)
#pragma unroll
      for (int nj = 0; nj < 8; ++nj) {
        f16x8 rf = *(const f16x8*)&Rl[(nj * 16 + ln) * KP + ks * 32 + 8 * lg];
        mw[nj] = __builtin_amdgcn_mfma_f32_16x16x32_f16(aqr[ks], rf, mw[nj], 0, 0, 0);
      }
    // park M in LDS (wave-private rows), then shear-gather BD[qi,ki]=M[qi,ki-qi+63]
#pragma unroll
    for (int nj = 0; nj < 8; ++nj)
#pragma unroll
      for (int r = 0; r < 4; ++r)
        Ml[(wv * 16 + 4 * lg + r) * 136 + nj * 16 + ln] = (f16)mw[nj][r];

#pragma unroll
    for (int ni = 0; ni < 4; ++ni)
#pragma unroll
      for (int r = 0; r < 4; ++r) {
        int qi = wv * 16 + 4 * lg + r;
        int ki = ni * 16 + ln;
        float bd = (float)Ml[qi * 136 + (ki - qi + 63)];
        float s = (sc[ni][r] + bd) * 0.125f;
        if (k0 + ki > q0 + qi) s = -1e30f;  // strict causal mask
        sc[ni][r] = s;
      }

    // online softmax (row groups of 16 lanes)
#pragma unroll
    for (int r = 0; r < 4; ++r) {
      float mx = sc[0][r];
#pragma unroll
      for (int ni = 1; ni < 4; ++ni) mx = fmaxf(mx, sc[ni][r]);
#pragma unroll
      for (int off = 1; off < 16; off <<= 1) mx = fmaxf(mx, __shfl_xor(mx, off, 16));
      float mnew = fmaxf(mrun[r], mx);
      float corr = __expf(mrun[r] - mnew);
      mrun[r] = mnew;
      float rs = 0.f;
#pragma unroll
      for (int ni = 0; ni < 4; ++ni) {
        float p = __expf(sc[ni][r] - mnew);
        sc[ni][r] = p;
        rs += p;
      }
#pragma unroll
      for (int off = 1; off < 16; off <<= 1) rs += __shfl_xor(rs, off, 16);
      lrun[r] = lrun[r] * corr + rs;
#pragma unroll
      for (int ni = 0; ni < 4; ++ni) oacc[ni][r] *= corr;
    }

    // P -> LDS (wave-private rows), reload as A-frags
#pragma unroll
    for (int ni = 0; ni < 4; ++ni)
#pragma unroll
      for (int r = 0; r < 4; ++r)
        Pl[(wv * 16 + 4 * lg + r) * KP + ni * 16 + ln] = (f16)sc[ni][r];

#pragma unroll
    for (int ks = 0; ks < 2; ++ks) {
      f16x8 pf = *(const f16x8*)&Pl[(wv * 16 + ln) * KP + ks * 32 + 8 * lg];
#pragma unroll
      for (int ni = 0; ni < 4; ++ni) {
        f16x8 vf = *(const f16x8*)&Vl[(ni * 16 + ln) * KP + ks * 32 + 8 * lg];
        oacc[ni] = __builtin_amdgcn_mfma_f32_16x16x32_f16(pf, vf, oacc[ni], 0, 0, 0);
      }
    }
  }

  // normalize + coalesced write via LDS (reuse Kl)
  __syncthreads();
#pragma unroll
  for (int ni = 0; ni < 4; ++ni)
#pragma unroll
    for (int r = 0; r < 4; ++r)
      Kl[(wv * 16 + 4 * lg + r) * KP + ni * 16 + ln] = (f16)(oacc[ni][r] / lrun[r]);
  __syncthreads();
  {
    f16* dst = attb + ((size_t)(b * 2048 + q0 + r4) * 16 + h) * 64 + c16;
    *(f16x8*)&dst[0] = *(const f16x8*)&Kl[r4 * KP + c16];
    *(f16x8*)&dst[8] = *(const f16x8*)&Kl[r4 * KP + c16 + 8];
  }
}

// ---------------- LayerNorm over last dim (1024), f32 out ----------------
__global__ __launch_bounds__(256) void ln_kernel(const float* __restrict__ pre,
                                                 const float* __restrict__ gamma,
                                                 const float* __restrict__ beta,
                                                 float* __restrict__ out) {
  __shared__ float red[8];
  const int row = blockIdx.x, t = threadIdx.x;
  f32x4 v = *(const f32x4*)&pre[(size_t)row * 1024 + t * 4];
  float s = v[0] + v[1] + v[2] + v[3];
  float s2 = v[0] * v[0] + v[1] * v[1] + v[2] * v[2] + v[3] * v[3];
#pragma unroll
  for (int off = 1; off < 64; off <<= 1) {
    s += __shfl_xor(s, off, 64);
    s2 += __shfl_xor(s2, off, 64);
  }
  if ((t & 63) == 0) {
    red[t >> 6] = s;
    red[(t >> 6) + 4] = s2;
  }
  __syncthreads();
  s = red[0] + red[1] + red[2] + red[3];
  s2 = red[4] + red[5] + red[6] + red[7];
  float mean = s * (1.f / 1024.f);
  float var = s2 * (1.f / 1024.f) - mean * mean;
  float rcp = rsqrtf(var + 1e-5f);
  f32x4 g = *(const f32x4*)&gamma[t * 4];
  f32x4 be = *(const f32x4*)&beta[t * 4];
  f32x4 o;
#pragma unroll
  for (int j = 0; j < 4; ++j) o[j] = (v[j] - mean) * rcp * g[j] + be[j];
  *(f32x4*)&out[(size_t)row * 1024 + t * 4] = o;
}

extern "C" void kernel_launch(void* const* d_in, const int* in_sizes, int n_in,
                              void* d_out, int out_size, void* d_ws, size_t ws_size,
                              hipStream_t stream) {
  const float* x = (const float*)d_in[0];
  // d_in[1] = mask (strict causal, known analytically -> unused)
  const float* pe = (const float*)d_in[2];
  const float* rr = (const float*)d_in[3];
  const float* rw = (const float*)d_in[4];
  const float* Wq = (const float*)d_in[5];
  const float* Wk = (const float*)d_in[6];
  const float* Wv = (const float*)d_in[7];
  const float* Wr = (const float*)d_in[8];
  const float* Wo = (const float*)d_in[9];
  const float* gamma = (const float*)d_in[10];
  const float* beta = (const float*)d_in[11];
  float* out = (float*)d_out;

  char* w = (char*)d_ws;
  auto alloc = [&](size_t bytes) {
    char* p = w;
    w += (bytes + 255) & ~(size_t)255;
    return p;
  };
  float* preln = (float*)alloc(4096ull * 1024 * 4);
  f16* xb = (f16*)alloc(4096ull * 1024 * 2);
  f16* pb = (f16*)alloc(2048ull * 1024 * 2);
  f16* WTq = (f16*)alloc(1024ull * 1024 * 2);
  f16* WTk = (f16*)alloc(1024ull * 1024 * 2);
  f16* WTv = (f16*)alloc(1024ull * 1024 * 2);
  f16* WTr = (f16*)alloc(1024ull * 1024 * 2);
  f16* WTo = (f16*)alloc(1024ull * 1024 * 2);
  f16* Qw = (f16*)alloc(4096ull * 1024 * 2);
  f16* Qr = (f16*)alloc(4096ull * 1024 * 2);
  f16* Kb = (f16*)alloc(4096ull * 1024 * 2);
  f16* VTb = (f16*)alloc(4096ull * 1024 * 2);
  f16* Rb = (f16*)alloc(2048ull * 1024 * 2);
  f16* attb = (f16*)alloc(4096ull * 1024 * 2);

  cast_kernel<<<4096, 256, 0, stream>>>(x, xb, 4096 * 1024 / 4);
  cast_kernel<<<2048, 256, 0, stream>>>(pe, pb, 2048 * 1024 / 4);
  dim3 tb(32, 8);
  wtrans_kernel<<<dim3(32, 32), tb, 0, stream>>>(Wq, WTq);
  wtrans_kernel<<<dim3(32, 32), tb, 0, stream>>>(Wk, WTk);
  wtrans_kernel<<<dim3(32, 32), tb, 0, stream>>>(Wv, WTv);
  wtrans_kernel<<<dim3(32, 32), tb, 0, stream>>>(Wr, WTr);
  wtrans_kernel<<<dim3(32, 32), tb, 0, stream>>>(Wo, WTo);

  gemm_kernel<0><<<dim3(8, 32), 256, 0, stream>>>(xb, WTq, Qw, Qr, nullptr, nullptr, rw, rr);
  gemm_kernel<1><<<dim3(8, 32), 256, 0, stream>>>(xb, WTk, Kb, nullptr, nullptr, nullptr, nullptr, nullptr);
  gemm_kernel<2><<<dim3(8, 32), 256, 0, stream>>>(xb, WTv, VTb, nullptr, nullptr, nullptr, nullptr, nullptr);
  gemm_kernel<3><<<dim3(8, 16), 256, 0, stream>>>(pb, WTr, Rb, nullptr, nullptr, nullptr, nullptr, nullptr);

  attn_kernel<<<dim3(32, 16, 2), 256, 0, stream>>>(Qw, Qr, Kb, VTb, Rb, attb);

  gemm_kernel<4><<<dim3(8, 32), 256, 0, stream>>>(attb, WTo, nullptr, nullptr, preln, x, nullptr, nullptr);
  ln_kernel<<<4096, 256, 0, stream>>>(preln, gamma, beta, out);
}